// Round 1
// baseline (392.196 us; speedup 1.0000x reference)
//
#include <hip/hip_runtime.h>
#include <cstddef>
#include <cstdint>

// Problem constants (from reference)
#define B_ 64
#define T_ 2000
#define L_ 400
#define M_ 80
#define EPSF 1e-8f
#define LOG_EPSF -18.420680743952367f   // logf(1e-8)
// GLOBAL_STEP=0 -> progress=0 -> sigma = clip(Lb*0.05, 3, 10)

#define NBLK 2048
#define BT_ (B_ * T_)
#define NTHREADS (NBLK * 256)
#define NWAVES (NBLK * 4)
#define L4_ (L_ / 4)          // 100 float4 per alignment row
#define TAIL_LANES (L4_ - 64) // 36 lanes carry the second float4

__device__ __forceinline__ float waveReduce(float v) {
#pragma unroll
  for (int m = 32; m >= 1; m >>= 1) v += __shfl_xor(v, m, 64);
  return v;
}

// Fused kernel. Latency-oriented rework vs previous version:
//  - alignment rows read as float4 (2 loads/row vs 7 scalar loads)
//  - software prefetch of the NEXT row's float4s before processing current
//  - KL reformulated: only S needs a wave reduce; W=sum(g*logp) folds into
//    pass 1; pass 2 recomputes the cheap gaussian exponent (only g[] kept)
//  - length arrays staged in LDS
//  - block-parity phase flip: half the blocks stream mel while the other
//    half do trans-heavy attention, co-scheduling BW and VALU pipes
__global__ __launch_bounds__(256) void fused_kernel(
    const float4* __restrict__ mo, const float4* __restrict__ mp,
    const float4* __restrict__ mt, const float* __restrict__ gx,
    const float* __restrict__ gz, const float* __restrict__ align,
    const int* __restrict__ mel_lengths, const int* __restrict__ text_lengths,
    double* __restrict__ ws) {
  __shared__ int sh_ml[B_];
  __shared__ int sh_tl[B_];
  if (threadIdx.x < B_) {
    sh_ml[threadIdx.x] = mel_lengths[threadIdx.x];
    sh_tl[threadIdx.x] = text_lengths[threadIdx.x];
  }
  __syncthreads();

  const int tid = blockIdx.x * 256 + threadIdx.x;
  const int lane = threadIdx.x & 63;
  const int wib = threadIdx.x >> 6;
  const int waveId = blockIdx.x * 4 + wib;

  float mel_acc = 0.f, gate_acc = 0.f, kl_acc = 0.f, ent_acc = 0.f;

  auto do_melgate = [&]() {
    // ---- mel L1 (masked) ----
    const int N4 = B_ * T_ * (M_ / 4);
#pragma unroll 2
    for (int i = tid; i < N4; i += NTHREADS) {
      int row = i / (M_ / 4);      // (b*T + t); 4 packed elems share a row
      int b = row / T_;
      int t = row - b * T_;
      if (t < sh_ml[b]) {
        float4 a = mo[i], c = mp[i], d = mt[i];
        mel_acc += fabsf(a.x - d.x) + fabsf(a.y - d.y) + fabsf(a.z - d.z) + fabsf(a.w - d.w)
                 + fabsf(c.x - d.x) + fabsf(c.y - d.y) + fabsf(c.z - d.z) + fabsf(c.w - d.w);
      }
    }
    // ---- gate BCE-with-logits ----
    for (int i = tid; i < BT_; i += NTHREADS) {
      float xv = gx[i], z = gz[i];
      gate_acc += fmaxf(xv, 0.f) - xv * z + log1pf(__expf(-fabsf(xv)));
    }
  };

  auto do_attn = [&]() {
    const float4* a4 = reinterpret_cast<const float4*>(align);
    int p = waveId;
    float4 c0, c1 = make_float4(0.f, 0.f, 0.f, 0.f);
    if (p < BT_) {
      const float4* r = a4 + (size_t)p * L4_;
      c0 = r[lane];
      if (lane < TAIL_LANES) c1 = r[64 + lane];
    }
    while (p < BT_) {
      // ---- prefetch next row (latency hidden under this row's compute) ----
      const int pn = p + NWAVES;
      float4 n0, n1;
      if (pn < BT_) {
        const float4* r = a4 + (size_t)pn * L4_;
        n0 = r[lane];
        if (lane < TAIL_LANES) n1 = r[64 + lane];
      }
      // ---- row parameters (LDS-resident lengths) ----
      int b = p / T_;
      int t = p - b * T_;
      int Lb = sh_tl[b];
      float sigma = fminf(fmaxf((float)Lb * 0.05f, 3.0f), 10.0f);  // progress=0
      float invsig = 1.0f / sigma;
      int epi = t * Lb / T_;        // floor-div, nonneg -> matches jnp //
      int lim = Lb - 1;
      if (epi > lim) epi = lim;
      float ep = (float)epi;

      // ---- pass 1: entropy, S = sum(g), W = sum(g * log p) ----
      float S = 0.f, W = 0.f;
      float g0[4], g1[4];
      const int l0 = 4 * lane;
      const float fl0 = (float)l0;
      {
        const float av[4] = {c0.x, c0.y, c0.z, c0.w};
#pragma unroll
        for (int j = 0; j < 4; ++j) {
          float as = fmaxf(av[j], EPSF);
          float lpv = __logf(as);
          ent_acc -= as * lpv;                 // entropy over all l (no mask)
          float z = (fl0 + (float)j - ep) * invsig;
          float e = -0.5f * z * z;
          float gv = ((l0 + j) < Lb) ? __expf(e) : 0.f;
          g0[j] = gv;
          S += gv;
          W += gv * lpv;
        }
      }
      const int l1 = 256 + 4 * lane;
      const float fl1 = (float)l1;
      if (lane < TAIL_LANES) {
        const float av[4] = {c1.x, c1.y, c1.z, c1.w};
#pragma unroll
        for (int j = 0; j < 4; ++j) {
          float as = fmaxf(av[j], EPSF);
          float lpv = __logf(as);
          ent_acc -= as * lpv;
          float z = (fl1 + (float)j - ep) * invsig;
          float e = -0.5f * z * z;
          float gv = ((l1 + j) < Lb) ? __expf(e) : 0.f;
          g1[j] = gv;
          S += gv;
          W += gv * lpv;
        }
      } else {
#pragma unroll
        for (int j = 0; j < 4; ++j) g1[j] = 0.f;
      }
      // ---- only S needs the cross-lane reduce ----
      float St = waveReduce(S);
      float Se = St + EPSF;
      float inv = 1.0f / Se;
      float logSe = __logf(Se);
      // ---- pass 2: K = sum(g * lt), exponent recomputed (no arrays) ----
      float K = 0.f;
#pragma unroll
      for (int j = 0; j < 4; ++j) {
        float z = (fl0 + (float)j - ep) * invsig;
        float e = -0.5f * z * z;
        float lt = fmaxf(e - logSe, LOG_EPSF);  // log(max(target,eps)), monotone
        K += g0[j] * lt;
      }
#pragma unroll
      for (int j = 0; j < 4; ++j) {
        float z = (fl1 + (float)j - ep) * invsig;
        float e = -0.5f * z * z;
        float lt = fmaxf(e - logSe, LOG_EPSF);
        K += g1[j] * lt;                        // g1=0 for pad lanes -> 0
      }
      kl_acc += inv * (K - W);
      // ---- advance pipeline ----
      p = pn; c0 = n0; c1 = n1;
    }
  };

  // Block-parity phase flip: co-schedule BW-bound mel with trans-bound attn.
  if (blockIdx.x & 1) { do_attn(); do_melgate(); }
  else                { do_melgate(); do_attn(); }

  // ---- block reduction of all 4 quantities ----
  float w0 = waveReduce(mel_acc);
  float w1 = waveReduce(gate_acc);
  float w2 = waveReduce(kl_acc);
  float w3 = waveReduce(ent_acc);
  __shared__ double sh[4][4];
  if (lane == 0) {
    sh[wib][0] = (double)w0; sh[wib][1] = (double)w1;
    sh[wib][2] = (double)w2; sh[wib][3] = (double)w3;
  }
  __syncthreads();
  if (threadIdx.x == 0) {
    ws[blockIdx.x]            = sh[0][0] + sh[1][0] + sh[2][0] + sh[3][0];
    ws[NBLK + blockIdx.x]     = sh[0][1] + sh[1][1] + sh[2][1] + sh[3][1];
    ws[2 * NBLK + blockIdx.x] = sh[0][2] + sh[1][2] + sh[2][2] + sh[3][2];
    ws[3 * NBLK + blockIdx.x] = sh[0][3] + sh[1][3] + sh[2][3] + sh[3][3];
  }
}

// ---------------- finalize ----------------
__device__ double segSum(const double* __restrict__ p, int n, double* sh) {
  double a = 0.0;
  for (int i = threadIdx.x; i < n; i += 256) a += p[i];
  sh[threadIdx.x] = a;
  __syncthreads();
  for (int s = 128; s > 0; s >>= 1) {
    if ((int)threadIdx.x < s) sh[threadIdx.x] += sh[threadIdx.x + s];
    __syncthreads();
  }
  double r = sh[0];
  __syncthreads();
  return r;
}

__global__ __launch_bounds__(256) void finalize_kernel(
    const double* __restrict__ ws, const int* __restrict__ mel_lengths,
    float* __restrict__ out) {
  __shared__ double sh[256];
  double mel_sum  = segSum(ws, NBLK, sh);
  double gate_sum = segSum(ws + NBLK, NBLK, sh);
  double kl_sum   = segSum(ws + 2 * NBLK, NBLK, sh);
  double ent_sum  = segSum(ws + 3 * NBLK, NBLK, sh);
  if (threadIdx.x == 0) {
    long nv = 0;
    for (int b = 0; b < B_; ++b) nv += mel_lengths[b];
    double n_valid = (double)nv * (double)M_;
    float loss_mel  = (float)(mel_sum / n_valid);
    float loss_gate = (float)(gate_sum / (double)(B_ * T_));
    float kl  = (float)(kl_sum / (double)(B_ * T_));
    kl = fminf(kl, 150.0f);
    float ent = (float)(ent_sum / (double)(B_ * T_));
    float ratio = fmaxf(ent / 3.5f, 0.0f);
    float weight = (ent <= 3.5f) ? fmaxf(0.2f, 1.0f * ratio) : 1.0f;
    out[0] = loss_mel + loss_gate + weight * kl;
    out[1] = loss_mel;
    out[2] = loss_gate;
    out[3] = kl;
  }
}

extern "C" void kernel_launch(void* const* d_in, const int* in_sizes, int n_in,
                              void* d_out, int out_size, void* d_ws, size_t ws_size,
                              hipStream_t stream) {
  const float* mel_out_postnet = (const float*)d_in[0];
  const float* mel_out         = (const float*)d_in[1];
  const float* gate_out        = (const float*)d_in[2];
  const float* alignments      = (const float*)d_in[3];
  const float* mel_target      = (const float*)d_in[4];
  const float* gate_target     = (const float*)d_in[5];
  const int*   mel_lengths     = (const int*)d_in[6];
  const int*   text_lengths    = (const int*)d_in[7];
  float* out = (float*)d_out;
  double* ws = (double*)d_ws;

  fused_kernel<<<dim3(NBLK), dim3(256), 0, stream>>>(
      (const float4*)mel_out, (const float4*)mel_out_postnet,
      (const float4*)mel_target, gate_out, gate_target,
      alignments, mel_lengths, text_lengths, ws);
  finalize_kernel<<<dim3(1), dim3(256), 0, stream>>>(ws, mel_lengths, out);
}

// Round 3
// 386.098 us; speedup vs baseline: 1.0158x; 1.0158x over previous
//
#include <hip/hip_runtime.h>
#include <cstddef>
#include <cstdint>

// Problem constants (from reference)
#define B_ 64
#define T_ 2000
#define L_ 400
#define M_ 80
#define EPSF 1e-8f
#define LOG2_EPSF -26.575424759098897f  // log2(1e-8)
#define LN2 0.6931471805599453          // used once in finalize
// GLOBAL_STEP=0 -> progress=0 -> sigma = clip(Lb*0.05, 3, 10); Lb>=200 -> sigma==10

#define NBLK 2048
#define BT_ (B_ * T_)                   // 128000
#define NTHREADS (NBLK * 256)
#define NWAVES (NBLK * 4)               // 8192
#define L4_ 100                         // float4 per alignment row
#define TAIL_LANES 36                   // lanes carrying the 2nd float4
#define N4_ (B_ * T_ * (M_ / 4))        // 2,560,000 float4 triples (mel)
#define NCH_ (N4_ / 64)                 // 40,000 chunks of 64 float4 (exact)
#define MAXK 16                         // ceil(128000/8192) attn rows/wave
#define MELK 5                          // ceil(40000/8192) mel chunks/wave

// clang ext vector: required by __builtin_nontemporal_load (HIP float4 is not)
typedef float vf4 __attribute__((ext_vector_type(4)));

// Fast log2/exp2 via direct gfx950 VALU ops (v_log_f32 / v_exp_f32)
#define LOG2F(x) __builtin_amdgcn_logf(x)
#define EXP2F(x) __builtin_amdgcn_exp2f(x)

__device__ __forceinline__ float waveReduce(float v) {
#pragma unroll
  for (int m = 32; m >= 1; m >>= 1) v += __shfl_xor(v, m, 64);
  return v;
}

// Single interleaved loop per wave: each iteration
//   1) prefetch next attention row (2 float4 loads)
//   2) issue one mel chunk's 3 nontemporal vf4 loads
//   3) attn pass1 (log2-domain), wave-reduce S, pass2 (stored g, recomputed e)
//   4) consume the mel chunk (loads have a full compute phase to land)
// keeps ~5 independent loads in flight per wave continuously (MLP fix) and
// co-schedules mel VALU work under attn's shuffle/trans stalls.
__global__ __launch_bounds__(256) void fused_kernel(
    const vf4* __restrict__ mo, const vf4* __restrict__ mp,
    const vf4* __restrict__ mt, const float* __restrict__ gx,
    const float* __restrict__ gz, const float* __restrict__ align,
    const int* __restrict__ mel_lengths, const int* __restrict__ text_lengths,
    double* __restrict__ ws) {
  __shared__ int sh_ml[B_];
  __shared__ int sh_tl[B_];
  if (threadIdx.x < B_) {
    sh_ml[threadIdx.x] = mel_lengths[threadIdx.x];
    sh_tl[threadIdx.x] = text_lengths[threadIdx.x];
  }
  __syncthreads();

  const int tid = blockIdx.x * 256 + threadIdx.x;
  const int lane = threadIdx.x & 63;
  const int wib = threadIdx.x >> 6;
  const int waveId = blockIdx.x * 4 + wib;

  float mel_acc = 0.f, gate_acc = 0.f, kl_acc = 0.f, ent2_acc = 0.f;

  // ---- gate BCE-with-logits: exactly one element per thread (BT_ < NTHREADS)
  if (tid < BT_) {
    float xv = gx[tid], z = gz[tid];
    gate_acc = fmaxf(xv, 0.f) - xv * z + log1pf(__expf(-fabsf(xv)));
  }

  const float4* a4 = reinterpret_cast<const float4*>(align);
  const float fl0 = (float)(4 * lane);

  // ---- preload attention row 0 (waveId < 8192 <= BT_, always valid)
  float4 c0, c1 = make_float4(0.f, 0.f, 0.f, 0.f);
  {
    const float4* r = a4 + (size_t)waveId * L4_;
    c0 = r[lane];
    if (lane < TAIL_LANES) c1 = r[64 + lane];
  }

#pragma unroll 1
  for (int k = 0; k < MAXK; ++k) {
    const int p = waveId + k * NWAVES;       // current attn row
    const bool pv = (p < BT_);

    // ---- 1) prefetch next attn row ----
    float4 n0 = make_float4(0.f, 0.f, 0.f, 0.f), n1 = n0;
    const int pn = p + NWAVES;
    if (pn < BT_) {
      const float4* r = a4 + (size_t)pn * L4_;
      n0 = r[lane];
      if (lane < TAIL_LANES) n1 = r[64 + lane];
    }

    // ---- 2) issue mel chunk loads (nontemporal: don't evict align from L3) ----
    vf4 ma, mb, md;
    int mi = 0;
    bool mv = false;
    if (k < MELK) {
      int ch = waveId + k * NWAVES;
      mv = (ch < NCH_);
      if (mv) {
        mi = ch * 64 + lane;
        ma = __builtin_nontemporal_load(&mo[mi]);
        mb = __builtin_nontemporal_load(&mp[mi]);
        md = __builtin_nontemporal_load(&mt[mi]);
      }
    }

    // ---- 3) attention on row p (log2 domain) ----
    if (pv) {
      int b = p / T_;
      int t = p - b * T_;
      int Lb = sh_tl[b];
      float sigma = fminf(fmaxf((float)Lb * 0.05f, 3.0f), 10.0f);  // progress=0
      float invsig = 1.0f / sigma;
      int epi = t * Lb / T_;          // floor-div, nonneg -> matches jnp //
      int lim = Lb - 1;
      if (epi > lim) epi = lim;
      float ep = (float)epi;
      float cg = -0.7213475204444817f * invsig * invsig;  // -0.5*log2e/sig^2
      float d0 = fl0 - ep;
      float d1 = d0 + 256.f;

      float S = 0.f, W2 = 0.f;
      float gs[8];
#pragma unroll
      for (int j = 4; j < 8; ++j) gs[j] = 0.f;

      // c0 half: l in [0,256)
      {
        const float av[4] = {c0.x, c0.y, c0.z, c0.w};
#pragma unroll
        for (int j = 0; j < 4; ++j) {
          float as = fmaxf(av[j], EPSF);
          float lp2 = LOG2F(as);                  // log2(pred)
          ent2_acc = fmaf(-as, lp2, ent2_acc);    // entropy (log2 units)
          float dj = d0 + (float)j;
          float e2 = dj * dj * cg;                // log2(g)
          float gv = EXP2F(e2);
          gv = ((4 * lane + j) < Lb) ? gv : 0.f;
          gs[j] = gv;
          S += gv;
          W2 = fmaf(gv, lp2, W2);
        }
      }
      // c1 half: l in [256,400). Gaussian computed only when it can be
      // nonzero in f32: 256-ep < 13.6*sigma (else g < 1e-40 -> vanishes).
      const bool c1w = (256.f - ep) < 13.6f * sigma;
      if (lane < TAIL_LANES) {
        const float av[4] = {c1.x, c1.y, c1.z, c1.w};
#pragma unroll
        for (int j = 0; j < 4; ++j) {
          float as = fmaxf(av[j], EPSF);
          float lp2 = LOG2F(as);
          ent2_acc = fmaf(-as, lp2, ent2_acc);
          if (c1w) {
            float dj = d1 + (float)j;
            float e2 = dj * dj * cg;
            float gv = EXP2F(e2);
            gv = ((256 + 4 * lane + j) < Lb) ? gv : 0.f;
            gs[4 + j] = gv;
            S += gv;
            W2 = fmaf(gv, lp2, W2);
          }
        }
      }

      float St = waveReduce(S);
      float Se = St + EPSF;
      float inv = 1.0f / Se;
      float lSe2 = LOG2F(Se);

      // pass2: K2 = sum g * max(log2(g) - log2(Se), log2(EPS)); e recomputed
      float K2 = 0.f;
#pragma unroll
      for (int j = 0; j < 4; ++j) {
        float dj = d0 + (float)j;
        float e2 = dj * dj * cg;
        K2 = fmaf(gs[j], fmaxf(e2 - lSe2, LOG2_EPSF), K2);
      }
      if (c1w) {
#pragma unroll
        for (int j = 0; j < 4; ++j) {
          float dj = d1 + (float)j;
          float e2 = dj * dj * cg;
          K2 = fmaf(gs[4 + j], fmaxf(e2 - lSe2, LOG2_EPSF), K2);
        }
      }
      kl_acc = fmaf(inv, K2 - W2, kl_acc);   // (log2 units; *ln2 in finalize)
    }

    // ---- 4) consume mel chunk (its loads aged a whole compute phase) ----
    if (mv) {
      int row = mi / 20;                 // 20 float4 per (b,t) row
      int b2 = row / T_;
      int t2 = row - b2 * T_;
      float s8 = fabsf(ma.x - md.x) + fabsf(ma.y - md.y) + fabsf(ma.z - md.z) +
                 fabsf(ma.w - md.w) + fabsf(mb.x - md.x) + fabsf(mb.y - md.y) +
                 fabsf(mb.z - md.z) + fabsf(mb.w - md.w);
      mel_acc += (t2 < sh_ml[b2]) ? s8 : 0.f;
    }

    // ---- rotate attn pipeline ----
    c0 = n0;
    c1 = n1;
  }

  // ---- block reduction of all 4 quantities ----
  float w0 = waveReduce(mel_acc);
  float w1 = waveReduce(gate_acc);
  float w2 = waveReduce(kl_acc);
  float w3 = waveReduce(ent2_acc);
  __shared__ double sh[4][4];
  if (lane == 0) {
    sh[wib][0] = (double)w0; sh[wib][1] = (double)w1;
    sh[wib][2] = (double)w2; sh[wib][3] = (double)w3;
  }
  __syncthreads();
  if (threadIdx.x == 0) {
    ws[blockIdx.x]            = sh[0][0] + sh[1][0] + sh[2][0] + sh[3][0];
    ws[NBLK + blockIdx.x]     = sh[0][1] + sh[1][1] + sh[2][1] + sh[3][1];
    ws[2 * NBLK + blockIdx.x] = sh[0][2] + sh[1][2] + sh[2][2] + sh[3][2];
    ws[3 * NBLK + blockIdx.x] = sh[0][3] + sh[1][3] + sh[2][3] + sh[3][3];
  }
}

// ---------------- finalize ----------------
__device__ double segSum(const double* __restrict__ p, int n, double* sh) {
  double a = 0.0;
  for (int i = threadIdx.x; i < n; i += 256) a += p[i];
  sh[threadIdx.x] = a;
  __syncthreads();
  for (int s = 128; s > 0; s >>= 1) {
    if ((int)threadIdx.x < s) sh[threadIdx.x] += sh[threadIdx.x + s];
    __syncthreads();
  }
  double r = sh[0];
  __syncthreads();
  return r;
}

__global__ __launch_bounds__(256) void finalize_kernel(
    const double* __restrict__ ws, const int* __restrict__ mel_lengths,
    float* __restrict__ out) {
  __shared__ double sh[256];
  double mel_sum  = segSum(ws, NBLK, sh);
  double gate_sum = segSum(ws + NBLK, NBLK, sh);
  double kl_sum   = segSum(ws + 2 * NBLK, NBLK, sh);
  double ent_sum  = segSum(ws + 3 * NBLK, NBLK, sh);
  if (threadIdx.x == 0) {
    long nv = 0;
    for (int b = 0; b < B_; ++b) nv += mel_lengths[b];
    double n_valid = (double)nv * (double)M_;
    float loss_mel  = (float)(mel_sum / n_valid);
    float loss_gate = (float)(gate_sum / (double)(B_ * T_));
    float kl  = (float)(kl_sum * LN2 / (double)(B_ * T_));   // log2 -> ln
    kl = fminf(kl, 150.0f);
    float ent = (float)(ent_sum * LN2 / (double)(B_ * T_));  // log2 -> ln
    float ratio = fmaxf(ent / 3.5f, 0.0f);
    float weight = (ent <= 3.5f) ? fmaxf(0.2f, 1.0f * ratio) : 1.0f;
    out[0] = loss_mel + loss_gate + weight * kl;
    out[1] = loss_mel;
    out[2] = loss_gate;
    out[3] = kl;
  }
}

extern "C" void kernel_launch(void* const* d_in, const int* in_sizes, int n_in,
                              void* d_out, int out_size, void* d_ws, size_t ws_size,
                              hipStream_t stream) {
  const float* mel_out_postnet = (const float*)d_in[0];
  const float* mel_out         = (const float*)d_in[1];
  const float* gate_out        = (const float*)d_in[2];
  const float* alignments      = (const float*)d_in[3];
  const float* mel_target      = (const float*)d_in[4];
  const float* gate_target     = (const float*)d_in[5];
  const int*   mel_lengths     = (const int*)d_in[6];
  const int*   text_lengths    = (const int*)d_in[7];
  float* out = (float*)d_out;
  double* ws = (double*)d_ws;

  fused_kernel<<<dim3(NBLK), dim3(256), 0, stream>>>(
      (const vf4*)mel_out, (const vf4*)mel_out_postnet,
      (const vf4*)mel_target, gate_out, gate_target,
      alignments, mel_lengths, text_lengths, ws);
  finalize_kernel<<<dim3(1), dim3(256), 0, stream>>>(ws, mel_lengths, out);
}

// Round 4
// 378.007 us; speedup vs baseline: 1.0375x; 1.0214x over previous
//
#include <hip/hip_runtime.h>
#include <cstddef>
#include <cstdint>

// Problem constants (from reference)
#define B_ 64
#define T_ 2000
#define L_ 400
#define M_ 80
#define EPSF 1e-8f
#define LOG2_EPSF -26.575424759098897f  // log2(1e-8)
#define LN2 0.6931471805599453          // used once in finalize
// GLOBAL_STEP=0 -> progress=0 -> sigma = clip(Lb*0.05, 3, 10)

#define NBLK 2048
#define BT_ (B_ * T_)                   // 128000
#define NW_ (NBLK * 4)                  // 8192 waves
#define PAIRS 8                         // 16 rows/wave as 8 dual-row pairs
#define PSTRIDE (2 * NW_)               // 16384
#define L4_ 100                         // float4 per alignment row
#define TAIL_LANES 36                   // lanes carrying the 2nd float4
#define MELW 128                        // waves per batch b (8192/64)
#define MELB4 (T_ * (M_ / 4))           // 40000 float4 per batch slab

// Fast log2/exp2 via direct gfx950 VALU ops (v_log_f32 / v_exp_f32)
#define LOG2F(x) __builtin_amdgcn_logf(x)
#define EXP2F(x) __builtin_amdgcn_exp2f(x)

__device__ __forceinline__ float waveReduce(float v) {
#pragma unroll
  for (int m = 32; m >= 1; m >>= 1) v += __shfl_xor(v, m, 64);
  return v;
}

// Two independent reduce chains interleaved -> cross-lane latency overlaps.
__device__ __forceinline__ void waveReduce2(float& a, float& b) {
#pragma unroll
  for (int m = 32; m >= 1; m >>= 1) {
    float ta = __shfl_xor(a, m, 64);
    float tb = __shfl_xor(b, m, 64);
    a += ta;
    b += tb;
  }
}

// Dual-row attention + prefix-bounded mel, all in one persistent loop.
//  - mel: masked sum == unmasked sum over i < ml[b]*20 float4 (prefix mask)
//    -> no divisions, no masks, skips reading masked data (~31 MB less HBM)
//  - attn: 2 rows per iteration -> two independent log/exp/shuffle chains
//    overlap; per-b constants staged in LDS; pair prefetched 1 ahead
__global__ __launch_bounds__(256) void fused_kernel(
    const float4* __restrict__ mo, const float4* __restrict__ mp,
    const float4* __restrict__ mt, const float* __restrict__ gx,
    const float* __restrict__ gz, const float* __restrict__ align,
    const int* __restrict__ mel_lengths, const int* __restrict__ text_lengths,
    double* __restrict__ ws) {
  __shared__ int sh_tl[B_];
  __shared__ int sh_bound[B_];
  __shared__ float sh_cg[B_];
  __shared__ float sh_thr[B_];
  if (threadIdx.x < B_) {
    int tl = text_lengths[threadIdx.x];
    sh_tl[threadIdx.x] = tl;
    sh_bound[threadIdx.x] = mel_lengths[threadIdx.x] * (M_ / 4);
    float sigma = fminf(fmaxf((float)tl * 0.05f, 3.0f), 10.0f);
    float invsig = 1.0f / sigma;
    sh_cg[threadIdx.x] = -0.7213475204444817f * invsig * invsig;  // -log2e/2sig^2
    sh_thr[threadIdx.x] = 256.0f - 13.6f * sigma;  // c1 half active iff ep > thr
  }
  __syncthreads();

  const int tid = blockIdx.x * 256 + threadIdx.x;
  const int lane = threadIdx.x & 63;
  const int wib = threadIdx.x >> 6;
  const int waveId = blockIdx.x * 4 + wib;

  float mel_acc = 0.f, gate_acc = 0.f, kl_acc = 0.f, ent2_acc = 0.f;

  // ---- gate BCE-with-logits: one element per thread (BT_ < grid threads) ----
  if (tid < BT_) {
    float xv = gx[tid], z = gz[tid];
    gate_acc = fmaxf(xv, 0.f) - xv * z + log1pf(__expf(-fabsf(xv)));
  }

  // ---- mel slab parameters (wave-uniform b) ----
  const int b_mel = waveId >> 7;          // 128 waves per batch
  const int melq = waveId & (MELW - 1);
  const int melBound = sh_bound[b_mel];
  const float4* melBaseO = mo + (size_t)b_mel * MELB4;
  const float4* melBaseP = mp + (size_t)b_mel * MELB4;
  const float4* melBaseT = mt + (size_t)b_mel * MELB4;

  const float4* a4 = reinterpret_cast<const float4*>(align);
  const float fl0 = (float)(4 * lane);
  const float4 f4z = make_float4(0.f, 0.f, 0.f, 0.f);

  float gsA[8], gsB[8];

  // pass1: entropy, S=sum g, W2=sum g*log2(pred); fills gs[8]
  auto pass1 = [&](int p, const float4& r0, const float4& r1, float* gs,
                   float& S, float& W2, float& d0, float& cg, int& Lb,
                   bool& c1w) {
    int b = p / T_;
    int t = p - b * T_;
    Lb = sh_tl[b];
    cg = sh_cg[b];
    int epi = t * Lb / T_;       // floor-div, nonneg -> matches jnp //
    int lim = Lb - 1;
    if (epi > lim) epi = lim;
    float ep = (float)epi;
    c1w = ep > sh_thr[b];
    d0 = fl0 - ep;
    S = 0.f;
    W2 = 0.f;
    const float a0[4] = {r0.x, r0.y, r0.z, r0.w};
#pragma unroll
    for (int j = 0; j < 4; ++j) {
      float as = fmaxf(a0[j], EPSF);
      float lp2 = LOG2F(as);
      ent2_acc = fmaf(-as, lp2, ent2_acc);
      float dj = d0 + (float)j;
      float e2 = dj * dj * cg;
      float gv = EXP2F(e2);
      gv = ((4 * lane + j) < Lb) ? gv : 0.f;
      gs[j] = gv;
      S += gv;
      W2 = fmaf(gv, lp2, W2);
    }
    if (lane < TAIL_LANES) {
      const float a1[4] = {r1.x, r1.y, r1.z, r1.w};
#pragma unroll
      for (int j = 0; j < 4; ++j) {
        float as = fmaxf(a1[j], EPSF);
        float lp2 = LOG2F(as);
        ent2_acc = fmaf(-as, lp2, ent2_acc);
        float gv = 0.f;
        if (c1w) {
          float dj = d0 + 256.f + (float)j;
          float e2 = dj * dj * cg;
          gv = EXP2F(e2);
          gv = ((256 + 4 * lane + j) < Lb) ? gv : 0.f;
          S += gv;
          W2 = fmaf(gv, lp2, W2);
        }
        gs[4 + j] = gv;
      }
    } else {
#pragma unroll
      for (int j = 0; j < 4; ++j) gs[4 + j] = 0.f;
    }
  };

  // pass2: K2 = sum g*max(log2 g - log2 Se, log2 eps); kl += (K2-W2)/Se
  auto pass2 = [&](const float* gs, float d0, float cg, float S, float W2,
                   bool c1w) {
    float Se = S + EPSF;
    float inv = 1.0f / Se;
    float lSe2 = LOG2F(Se);
    float K2 = 0.f;
#pragma unroll
    for (int j = 0; j < 4; ++j) {
      float dj = d0 + (float)j;
      float e2 = dj * dj * cg;
      K2 = fmaf(gs[j], fmaxf(e2 - lSe2, LOG2_EPSF), K2);
    }
    if (c1w) {
#pragma unroll
      for (int j = 0; j < 4; ++j) {
        float dj = d0 + 256.f + (float)j;
        float e2 = dj * dj * cg;
        K2 = fmaf(gs[4 + j], fmaxf(e2 - lSe2, LOG2_EPSF), K2);
      }
    }
    kl_acc = fmaf(inv, K2 - W2, kl_acc);
  };

  // ---- preload pair 0 (rows waveId, waveId+NW_; both < 16384 < BT_) ----
  float4 a0, a1 = f4z, b0, b1 = f4z;
  {
    const float4* r = a4 + (size_t)waveId * L4_;
    a0 = r[lane];
    if (lane < TAIL_LANES) a1 = r[64 + lane];
    const float4* r2 = a4 + (size_t)(waveId + NW_) * L4_;
    b0 = r2[lane];
    if (lane < TAIL_LANES) b1 = r2[64 + lane];
  }

#pragma unroll 1
  for (int kp = 0; kp < PAIRS; ++kp) {
    const int pA = waveId + kp * PSTRIDE;     // always < BT_
    const int pB = pA + NW_;
    const bool bv = (pB < BT_);               // wave-uniform (false only kp=7)

    float SA, W2A, d0A, cgA;
    int LbA;
    bool cwA;
    pass1(pA, a0, a1, gsA, SA, W2A, d0A, cgA, LbA, cwA);

    // prefetch next pair row A (a-buffers are dead now)
    float4 na0 = f4z, na1 = f4z, nb0 = f4z, nb1 = f4z;
    const int qA = pA + PSTRIDE;
    if (kp + 1 < PAIRS) {                     // qA < BT_ guaranteed
      const float4* r = a4 + (size_t)qA * L4_;
      na0 = r[lane];
      if (lane < TAIL_LANES) na1 = r[64 + lane];
    }

    float SB = 0.f, W2B = 0.f, d0B = 0.f, cgB = 0.f;
    int LbB = 0;
    bool cwB = false;
    if (bv) pass1(pB, b0, b1, gsB, SB, W2B, d0B, cgB, LbB, cwB);

    // prefetch next pair row B
    const int qB = qA + NW_;
    if (kp + 1 < PAIRS && qB < BT_) {
      const float4* r = a4 + (size_t)qB * L4_;
      nb0 = r[lane];
      if (lane < TAIL_LANES) nb1 = r[64 + lane];
    }

    // issue mel chunk loads (prefix-bounded slab: no div, no mask)
    float4 ma, mb, md;
    bool mv = false;
    if (kp < 5) {
      int i = melq * 64 + lane + kp * (MELW * 64);
      mv = (i < melBound);
      if (mv) {
        ma = melBaseO[i];
        mb = melBaseP[i];
        md = melBaseT[i];
      }
    }

    waveReduce2(SA, SB);
    pass2(gsA, d0A, cgA, SA, W2A, cwA);
    if (bv) pass2(gsB, d0B, cgB, SB, W2B, cwB);

    // consume mel chunk (loads aged past both pass2 phases)
    if (mv) {
      mel_acc += fabsf(ma.x - md.x) + fabsf(ma.y - md.y) + fabsf(ma.z - md.z) +
                 fabsf(ma.w - md.w) + fabsf(mb.x - md.x) + fabsf(mb.y - md.y) +
                 fabsf(mb.z - md.z) + fabsf(mb.w - md.w);
    }

    // rotate pipeline
    a0 = na0; a1 = na1; b0 = nb0; b1 = nb1;
  }

  // ---- block reduction of all 4 quantities ----
  float w0 = waveReduce(mel_acc);
  float w1 = waveReduce(gate_acc);
  float w2 = waveReduce(kl_acc);
  float w3 = waveReduce(ent2_acc);
  __shared__ double sh[4][4];
  if (lane == 0) {
    sh[wib][0] = (double)w0; sh[wib][1] = (double)w1;
    sh[wib][2] = (double)w2; sh[wib][3] = (double)w3;
  }
  __syncthreads();
  if (threadIdx.x == 0) {
    ws[blockIdx.x]            = sh[0][0] + sh[1][0] + sh[2][0] + sh[3][0];
    ws[NBLK + blockIdx.x]     = sh[0][1] + sh[1][1] + sh[2][1] + sh[3][1];
    ws[2 * NBLK + blockIdx.x] = sh[0][2] + sh[1][2] + sh[2][2] + sh[3][2];
    ws[3 * NBLK + blockIdx.x] = sh[0][3] + sh[1][3] + sh[2][3] + sh[3][3];
  }
}

// ---------------- finalize ----------------
__device__ double segSum(const double* __restrict__ p, int n, double* sh) {
  double a = 0.0;
  for (int i = threadIdx.x; i < n; i += 256) a += p[i];
  sh[threadIdx.x] = a;
  __syncthreads();
  for (int s = 128; s > 0; s >>= 1) {
    if ((int)threadIdx.x < s) sh[threadIdx.x] += sh[threadIdx.x + s];
    __syncthreads();
  }
  double r = sh[0];
  __syncthreads();
  return r;
}

__global__ __launch_bounds__(256) void finalize_kernel(
    const double* __restrict__ ws, const int* __restrict__ mel_lengths,
    float* __restrict__ out) {
  __shared__ double sh[256];
  __shared__ int sh_nv[64];
  if (threadIdx.x < B_) sh_nv[threadIdx.x] = mel_lengths[threadIdx.x];
  double mel_sum  = segSum(ws, NBLK, sh);
  double gate_sum = segSum(ws + NBLK, NBLK, sh);
  double kl_sum   = segSum(ws + 2 * NBLK, NBLK, sh);
  double ent_sum  = segSum(ws + 3 * NBLK, NBLK, sh);
  if (threadIdx.x == 0) {
    long nv = 0;
    for (int b = 0; b < B_; ++b) nv += sh_nv[b];
    double n_valid = (double)nv * (double)M_;
    float loss_mel  = (float)(mel_sum / n_valid);
    float loss_gate = (float)(gate_sum / (double)(B_ * T_));
    float kl  = (float)(kl_sum * LN2 / (double)(B_ * T_));   // log2 -> ln
    kl = fminf(kl, 150.0f);
    float ent = (float)(ent_sum * LN2 / (double)(B_ * T_));  // log2 -> ln
    float ratio = fmaxf(ent / 3.5f, 0.0f);
    float weight = (ent <= 3.5f) ? fmaxf(0.2f, 1.0f * ratio) : 1.0f;
    out[0] = loss_mel + loss_gate + weight * kl;
    out[1] = loss_mel;
    out[2] = loss_gate;
    out[3] = kl;
  }
}

extern "C" void kernel_launch(void* const* d_in, const int* in_sizes, int n_in,
                              void* d_out, int out_size, void* d_ws, size_t ws_size,
                              hipStream_t stream) {
  const float* mel_out_postnet = (const float*)d_in[0];
  const float* mel_out         = (const float*)d_in[1];
  const float* gate_out        = (const float*)d_in[2];
  const float* alignments      = (const float*)d_in[3];
  const float* mel_target      = (const float*)d_in[4];
  const float* gate_target     = (const float*)d_in[5];
  const int*   mel_lengths     = (const int*)d_in[6];
  const int*   text_lengths    = (const int*)d_in[7];
  float* out = (float*)d_out;
  double* ws = (double*)d_ws;

  fused_kernel<<<dim3(NBLK), dim3(256), 0, stream>>>(
      (const float4*)mel_out, (const float4*)mel_out_postnet,
      (const float4*)mel_target, gate_out, gate_target,
      alignments, mel_lengths, text_lengths, ws);
  finalize_kernel<<<dim3(1), dim3(256), 0, stream>>>(ws, mel_lengths, out);
}